// Round 1
// baseline (502.879 us; speedup 1.0000x reference)
//
#include <hip/hip_runtime.h>
#include <hip/hip_bf16.h>
#include <stdint.h>

#define DI __device__ __forceinline__

typedef __bf16 bf16x8 __attribute__((ext_vector_type(8)));
typedef __bf16 bf16x4 __attribute__((ext_vector_type(4)));
typedef float  f32x4  __attribute__((ext_vector_type(4)));

constexpr int Bc = 2, Sc = 2048, Dm = 1024, Hc = 16;
constexpr int Mrows = Bc * Sc;          // 4096
constexpr float LOG2E = 1.4426950408889634f;

// ---------------------------------------------------------------- async 16B global->LDS
DI void async16(void* lds, const void* g) {
  __builtin_amdgcn_global_load_lds(
      (const __attribute__((address_space(1))) void*)g,
      (__attribute__((address_space(3))) void*)lds, 16, 0, 0);
}

// ---------------------------------------------------------------- fp32 -> bf16 (x8 per thread)
__global__ void cvt_bf16(const float* __restrict__ in, __bf16* __restrict__ out, int n8) {
  int i = blockIdx.x * blockDim.x + threadIdx.x;
  if (i >= n8) return;
  const f32x4* in4 = (const f32x4*)in;
  f32x4 a = in4[2 * i], b = in4[2 * i + 1];
  bf16x8 o;
#pragma unroll
  for (int j = 0; j < 4; ++j) { o[j] = (__bf16)a[j]; o[4 + j] = (__bf16)b[j]; }
  ((bf16x8*)out)[i] = o;
}

// ---------------------------------------------------------------- mask int32 -> bitmask
__global__ void pack_mask(const int* __restrict__ m, unsigned long long* __restrict__ bits) {
  const int total = Bc * Sc * Sc;
  const int nth = gridDim.x * blockDim.x;
  for (int i = blockIdx.x * blockDim.x + threadIdx.x; i < total; i += nth) {
    unsigned long long b = __ballot(m[i] != 0);
    if ((threadIdx.x & 63) == 0) bits[i >> 6] = b;
  }
}

// ---------------------------------------------------------------- GEMM: C[M=4096][N=1024] = A[M][1024] * Bw[N][1024]^T + bias
// OUTMODE 0: fp32 row-major to Cout
// OUTMODE 1: bf16 head-major [B][H][S][64]
// OUTMODE 2: bf16 transposed [B][H][64][S]   (for V)
template <int OUTMODE>
__global__ __launch_bounds__(256)
void gemm_bt(const __bf16* __restrict__ A, const __bf16* __restrict__ Bw,
             const float* __restrict__ bias, void* __restrict__ Cout) {
  __shared__ __bf16 As[128 * 32];
  __shared__ __bf16 Bs[128 * 32];
  const int t = threadIdx.x;
  int bid = blockIdx.x;
  bid = (bid & 7) * 32 + (bid >> 3);          // XCD-contiguous swizzle (256 = 8*32)
  const int mt = bid >> 3, nt = bid & 7;      // 32 x 8 tiles of 128x128
  const int m0 = mt * 128, n0 = nt * 128;
  const int lane = t & 63, wv = t >> 6;
  const int lo = lane & 15, hi = lane >> 4;
  const int wm = (wv >> 1) * 64, wn = (wv & 1) * 64;
  const int rowA = t >> 2, kc8 = (t & 3) * 8;

  f32x4 acc[4][4] = {};

  for (int k0 = 0; k0 < 1024; k0 += 32) {
    __syncthreads();                          // protect LDS from prev-iter readers
    async16(&As[t * 8],        A  + (size_t)(m0 + rowA) * 1024      + k0 + kc8);
    async16(&As[t * 8 + 2048], A  + (size_t)(m0 + rowA + 64) * 1024 + k0 + kc8);
    async16(&Bs[t * 8],        Bw + (size_t)(n0 + rowA) * 1024      + k0 + kc8);
    async16(&Bs[t * 8 + 2048], Bw + (size_t)(n0 + rowA + 64) * 1024 + k0 + kc8);
    __syncthreads();                          // drains vmcnt before barrier
    bf16x8 af[4], bfr[4];
#pragma unroll
    for (int i = 0; i < 4; ++i)
      af[i] = *(const bf16x8*)&As[(wm + i * 16 + lo) * 32 + hi * 8];
#pragma unroll
    for (int j = 0; j < 4; ++j)
      bfr[j] = *(const bf16x8*)&Bs[(wn + j * 16 + lo) * 32 + hi * 8];
#pragma unroll
    for (int i = 0; i < 4; ++i)
#pragma unroll
      for (int j = 0; j < 4; ++j)
        acc[i][j] = __builtin_amdgcn_mfma_f32_16x16x32_bf16(af[i], bfr[j], acc[i][j], 0, 0, 0);
  }

  if constexpr (OUTMODE == 0) {
    float* C = (float*)Cout;
#pragma unroll
    for (int mi = 0; mi < 4; ++mi) {
      const int mbase = m0 + wm + mi * 16 + hi * 4;
#pragma unroll
      for (int ni = 0; ni < 4; ++ni) {
        const int n = n0 + wn + ni * 16 + lo;
        const float bb = bias[n];
#pragma unroll
        for (int r = 0; r < 4; ++r)
          C[(size_t)(mbase + r) * 1024 + n] = acc[mi][ni][r] + bb;
      }
    }
  } else if constexpr (OUTMODE == 1) {
    __bf16* C = (__bf16*)Cout;
#pragma unroll
    for (int mi = 0; mi < 4; ++mi) {
      const int mbase = m0 + wm + mi * 16 + hi * 4;
      const int b = mbase >> 11, s = mbase & 2047;
#pragma unroll
      for (int ni = 0; ni < 4; ++ni) {
        const int n = n0 + wn + ni * 16 + lo;
        const int h = n >> 6, d = n & 63;
        const float bb = bias[n];
        __bf16* p = C + ((size_t)(b * Hc + h) * Sc + s) * 64 + d;
#pragma unroll
        for (int r = 0; r < 4; ++r)
          p[(size_t)r * 64] = (__bf16)(acc[mi][ni][r] + bb);
      }
    }
  } else {
    __bf16* C = (__bf16*)Cout;
#pragma unroll
    for (int mi = 0; mi < 4; ++mi) {
      const int mbase = m0 + wm + mi * 16 + hi * 4;
      const int b = mbase >> 11, s0 = mbase & 2047;
#pragma unroll
      for (int ni = 0; ni < 4; ++ni) {
        const int n = n0 + wn + ni * 16 + lo;
        const int h = n >> 6, d = n & 63;
        const float bb = bias[n];
        bf16x4 pk;
#pragma unroll
        for (int r = 0; r < 4; ++r) pk[r] = (__bf16)(acc[mi][ni][r] + bb);
        *(bf16x4*)(C + ((size_t)(b * Hc + h) * 64 + d) * Sc + s0) = pk;
      }
    }
  }
}

// ---------------------------------------------------------------- flash attention
// Qh,Kh: [B][H][S][64] bf16 ; Vt: [B][H][64][S] bf16 ; out X: [B*S][1024] bf16
__global__ __launch_bounds__(256)
void attn_fwd(const __bf16* __restrict__ Qh, const __bf16* __restrict__ Kh,
              const __bf16* __restrict__ Vt, const unsigned long long* __restrict__ mbits,
              __bf16* __restrict__ X) {
  __shared__ __bf16 P[4][16][72];             // per-wave P tile, +8 pad kills bank conflicts
  int bid = blockIdx.x;
  bid = (bid & 7) * 128 + (bid >> 3);         // same (b,h) -> same XCD (1024 = 8*128)
  const int qt = bid & 31, h = (bid >> 5) & 15, b = bid >> 9;
  const int t = threadIdx.x, lane = t & 63, wv = t >> 6;
  const int lo = lane & 15, hi = lane >> 4;
  const int q0 = qt * 64 + wv * 16;

  const size_t headoff = (size_t)(b * Hc + h) * Sc * 64;
  const __bf16* Qp = Qh + headoff + (size_t)q0 * 64;
  const __bf16* Kp = Kh + headoff;
  const __bf16* Vp = Vt + headoff;            // [64][S]

  bf16x8 qf[2];
  qf[0] = *(const bf16x8*)&Qp[lo * 64 + hi * 8];
  qf[1] = *(const bf16x8*)&Qp[lo * 64 + 32 + hi * 8];

  f32x4 o[4] = {};
  float mr[4], lr[4];
#pragma unroll
  for (int r = 0; r < 4; ++r) { mr[r] = -1e38f; lr[r] = 0.f; }

  const unsigned long long* mrow = mbits + ((size_t)b * Sc + q0 + hi * 4) * (Sc / 64);

  for (int kb = 0; kb < Sc; kb += 64) {
    // ---- S = Q K^T for 64 keys
    f32x4 sc[4] = {};
#pragma unroll
    for (int kc = 0; kc < 4; ++kc) {
      const __bf16* kr = &Kp[(size_t)(kb + kc * 16 + lo) * 64 + hi * 8];
      bf16x8 k0f = *(const bf16x8*)kr;
      bf16x8 k1f = *(const bf16x8*)(kr + 32);
      sc[kc] = __builtin_amdgcn_mfma_f32_16x16x32_bf16(qf[0], k0f, sc[kc], 0, 0, 0);
      sc[kc] = __builtin_amdgcn_mfma_f32_16x16x32_bf16(qf[1], k1f, sc[kc], 0, 0, 0);
    }
    // ---- scale + mask (faithful: masked -> -1e-9, still in softmax)
    unsigned long long mb[4];
#pragma unroll
    for (int r = 0; r < 4; ++r) mb[r] = mrow[r * (Sc / 64) + (kb >> 6)];
    float pv[4][4], pmax[4];
#pragma unroll
    for (int r = 0; r < 4; ++r) pmax[r] = -1e38f;
#pragma unroll
    for (int kc = 0; kc < 4; ++kc)
#pragma unroll
      for (int r = 0; r < 4; ++r) {
        float s = sc[kc][r] * 0.125f;
        if (!((mb[r] >> (kc * 16 + lo)) & 1ull)) s = -1e-9f;
        pv[kc][r] = s;
        pmax[r] = fmaxf(pmax[r], s);
      }
    // row max across the 16 lanes of each row group
#pragma unroll
    for (int d = 1; d < 16; d <<= 1)
#pragma unroll
      for (int r = 0; r < 4; ++r) pmax[r] = fmaxf(pmax[r], __shfl_xor(pmax[r], d));
    float fs[4];
#pragma unroll
    for (int r = 0; r < 4; ++r) {
      float mn = fmaxf(mr[r], pmax[r]);
      fs[r] = exp2f((mr[r] - mn) * LOG2E);
      mr[r] = mn;
    }
    float rs[4] = {0.f, 0.f, 0.f, 0.f};
#pragma unroll
    for (int kc = 0; kc < 4; ++kc)
#pragma unroll
      for (int r = 0; r < 4; ++r) {
        float p = exp2f((pv[kc][r] - mr[r]) * LOG2E);
        pv[kc][r] = p;
        rs[r] += p;
      }
#pragma unroll
    for (int d = 1; d < 16; d <<= 1)
#pragma unroll
      for (int r = 0; r < 4; ++r) rs[r] += __shfl_xor(rs[r], d);
#pragma unroll
    for (int r = 0; r < 4; ++r) lr[r] = lr[r] * fs[r] + rs[r];
#pragma unroll
    for (int d0 = 0; d0 < 4; ++d0)
#pragma unroll
      for (int r = 0; r < 4; ++r) o[d0][r] *= fs[r];
    // ---- P -> LDS (bf16), re-layout into A-fragment
#pragma unroll
    for (int kc = 0; kc < 4; ++kc)
#pragma unroll
      for (int r = 0; r < 4; ++r)
        P[wv][hi * 4 + r][kc * 16 + lo] = (__bf16)pv[kc][r];
    // ---- O += P V  (V read transposed from global: contiguous 16B)
#pragma unroll
    for (int c = 0; c < 2; ++c) {
      bf16x8 pa = *(const bf16x8*)&P[wv][lo][c * 32 + hi * 8];
#pragma unroll
      for (int d0 = 0; d0 < 4; ++d0) {
        bf16x8 vf = *(const bf16x8*)&Vp[(size_t)(d0 * 16 + lo) * Sc + kb + c * 32 + hi * 8];
        o[d0] = __builtin_amdgcn_mfma_f32_16x16x32_bf16(pa, vf, o[d0], 0, 0, 0);
      }
    }
  }
  // ---- normalize + store [b][s][h*64+d]
  float inv[4];
#pragma unroll
  for (int r = 0; r < 4; ++r) inv[r] = 1.f / lr[r];
#pragma unroll
  for (int d0 = 0; d0 < 4; ++d0)
#pragma unroll
    for (int r = 0; r < 4; ++r)
      X[((size_t)b * Sc + q0 + hi * 4 + r) * 1024 + h * 64 + d0 * 16 + lo] =
          (__bf16)(o[d0][r] * inv[r]);
}

// ---------------------------------------------------------------- launcher
extern "C" void kernel_launch(void* const* d_in, const int* in_sizes, int n_in,
                              void* d_out, int out_size, void* d_ws, size_t ws_size,
                              hipStream_t stream) {
  const float* q  = (const float*)d_in[0];
  const float* k  = (const float*)d_in[1];
  const float* v  = (const float*)d_in[2];
  const int*   mask = (const int*)d_in[3];
  const float* Wq = (const float*)d_in[4];
  const float* bq = (const float*)d_in[5];
  const float* Wk = (const float*)d_in[6];
  const float* bk = (const float*)d_in[7];
  const float* Wv = (const float*)d_in[8];
  const float* bv = (const float*)d_in[9];
  const float* Wo = (const float*)d_in[10];
  const float* bo = (const float*)d_in[11];

  const size_t MB = 1u << 20;
  if (ws_size < 66 * MB) return;  // need 65 MB of scratch

  char* ws = (char*)d_ws;
  __bf16* wqb  = (__bf16*)(ws + 0 * MB);
  __bf16* wkb  = (__bf16*)(ws + 2 * MB);
  __bf16* wvb  = (__bf16*)(ws + 4 * MB);
  __bf16* wob  = (__bf16*)(ws + 6 * MB);
  __bf16* qbin = (__bf16*)(ws + 8 * MB);
  __bf16* kbin = (__bf16*)(ws + 16 * MB);
  __bf16* vbin = (__bf16*)(ws + 24 * MB);
  __bf16* Qh   = (__bf16*)(ws + 32 * MB);
  __bf16* Kh   = (__bf16*)(ws + 40 * MB);
  __bf16* Vt   = (__bf16*)(ws + 48 * MB);
  __bf16* Xat  = (__bf16*)(ws + 56 * MB);
  unsigned long long* mbits = (unsigned long long*)(ws + 64 * MB);

  const int nIn8 = Mrows * Dm / 8;   // 524288
  const int nW8  = Dm * Dm / 8;      // 131072
  cvt_bf16<<<nIn8 / 256, 256, 0, stream>>>(q, qbin, nIn8);
  cvt_bf16<<<nIn8 / 256, 256, 0, stream>>>(k, kbin, nIn8);
  cvt_bf16<<<nIn8 / 256, 256, 0, stream>>>(v, vbin, nIn8);
  cvt_bf16<<<nW8 / 256, 256, 0, stream>>>(Wq, wqb, nW8);
  cvt_bf16<<<nW8 / 256, 256, 0, stream>>>(Wk, wkb, nW8);
  cvt_bf16<<<nW8 / 256, 256, 0, stream>>>(Wv, wvb, nW8);
  cvt_bf16<<<nW8 / 256, 256, 0, stream>>>(Wo, wob, nW8);
  pack_mask<<<4096, 256, 0, stream>>>(mask, mbits);

  gemm_bt<1><<<256, 256, 0, stream>>>(qbin, wqb, bq, Qh);
  gemm_bt<1><<<256, 256, 0, stream>>>(kbin, wkb, bk, Kh);
  gemm_bt<2><<<256, 256, 0, stream>>>(vbin, wvb, bv, Vt);

  attn_fwd<<<1024, 256, 0, stream>>>(Qh, Kh, Vt, mbits, Xat);

  gemm_bt<0><<<256, 256, 0, stream>>>(Xat, wob, bo, (float*)d_out);
}

// Round 3
// 310.511 us; speedup vs baseline: 1.6195x; 1.6195x over previous
//
#include <hip/hip_runtime.h>
#include <hip/hip_bf16.h>
#include <stdint.h>

#define DI __device__ __forceinline__

typedef __bf16 bf16x8 __attribute__((ext_vector_type(8)));
typedef __bf16 bf16x4 __attribute__((ext_vector_type(4)));
typedef float  f32x4  __attribute__((ext_vector_type(4)));

constexpr int Bc = 2, Sc = 2048, Dm = 1024, Hc = 16;
constexpr int Mrows = Bc * Sc;          // 4096
constexpr float LOG2E = 1.4426950408889634f;

// ---------------------------------------------------------------- async 16B global->LDS
DI void async16(void* lds, const void* g) {
  __builtin_amdgcn_global_load_lds(
      (const __attribute__((address_space(1))) void*)g,
      (__attribute__((address_space(3))) void*)lds, 16, 0, 0);
}

// ---------------------------------------------------------------- fp32 -> bf16 fused converters
DI void cvt_one(const float* __restrict__ in, __bf16* __restrict__ out, int i) {
  const f32x4* in4 = (const f32x4*)in;
  f32x4 a = in4[2 * i], b = in4[2 * i + 1];
  bf16x8 o;
#pragma unroll
  for (int j = 0; j < 4; ++j) { o[j] = (__bf16)a[j]; o[4 + j] = (__bf16)b[j]; }
  ((bf16x8*)out)[i] = o;
}

__global__ void cvt3(const float* __restrict__ a, const float* __restrict__ b,
                     const float* __restrict__ c, __bf16* __restrict__ oa,
                     __bf16* __restrict__ ob, __bf16* __restrict__ oc, int n8) {
  int i = blockIdx.x * blockDim.x + threadIdx.x;
  if (i >= n8) return;
  cvt_one(a, oa, i); cvt_one(b, ob, i); cvt_one(c, oc, i);
}

__global__ void cvt4(const float* __restrict__ a, const float* __restrict__ b,
                     const float* __restrict__ c, const float* __restrict__ d,
                     __bf16* __restrict__ oa, __bf16* __restrict__ ob,
                     __bf16* __restrict__ oc, __bf16* __restrict__ od, int n8) {
  int i = blockIdx.x * blockDim.x + threadIdx.x;
  if (i >= n8) return;
  cvt_one(a, oa, i); cvt_one(b, ob, i); cvt_one(c, oc, i); cvt_one(d, od, i);
}

// ---------------------------------------------------------------- mask int32 -> bitmask
__global__ void pack_mask(const int* __restrict__ m, unsigned long long* __restrict__ bits) {
  const int total = Bc * Sc * Sc;
  const int nth = gridDim.x * blockDim.x;
  for (int i = blockIdx.x * blockDim.x + threadIdx.x; i < total; i += nth) {
    unsigned long long b = __ballot(m[i] != 0);
    if ((threadIdx.x & 63) == 0) bits[i >> 6] = b;
  }
}

// ---------------------------------------------------------------- GEMM core: 128x128 tile, K=1024
DI void gemm_core(const __bf16* __restrict__ A, const __bf16* __restrict__ Bw,
                  __bf16* As, __bf16* Bs, int m0, int n0, int t, f32x4 (&acc)[4][4]) {
  const int lane = t & 63, wv = t >> 6;
  const int lo = lane & 15, hi = lane >> 4;
  const int wm = (wv >> 1) * 64, wn = (wv & 1) * 64;
  const int rowA = t >> 2, kc8 = (t & 3) * 8;

  for (int k0 = 0; k0 < 1024; k0 += 32) {
    __syncthreads();                          // protect LDS from prev-iter readers
    async16(&As[t * 8],        A  + (size_t)(m0 + rowA) * 1024      + k0 + kc8);
    async16(&As[t * 8 + 2048], A  + (size_t)(m0 + rowA + 64) * 1024 + k0 + kc8);
    async16(&Bs[t * 8],        Bw + (size_t)(n0 + rowA) * 1024      + k0 + kc8);
    async16(&Bs[t * 8 + 2048], Bw + (size_t)(n0 + rowA + 64) * 1024 + k0 + kc8);
    __syncthreads();                          // drains vmcnt before barrier
    bf16x8 af[4], bfr[4];
#pragma unroll
    for (int i = 0; i < 4; ++i)
      af[i] = *(const bf16x8*)&As[(wm + i * 16 + lo) * 32 + hi * 8];
#pragma unroll
    for (int j = 0; j < 4; ++j)
      bfr[j] = *(const bf16x8*)&Bs[(wn + j * 16 + lo) * 32 + hi * 8];
#pragma unroll
    for (int i = 0; i < 4; ++i)
#pragma unroll
      for (int j = 0; j < 4; ++j)
        acc[i][j] = __builtin_amdgcn_mfma_f32_16x16x32_bf16(af[i], bfr[j], acc[i][j], 0, 0, 0);
  }
}

// ---------------------------------------------------------------- fused QKV projection
// which=0: Q -> Qh [B][H][S][64] ; which=1: K -> Kh same ; which=2: V -> Vt [B][H][64][S]
__global__ __launch_bounds__(256)
void gemm_qkv(const __bf16* __restrict__ Aq, const __bf16* __restrict__ Ak,
              const __bf16* __restrict__ Av, const __bf16* __restrict__ Wqb,
              const __bf16* __restrict__ Wkb, const __bf16* __restrict__ Wvb,
              const float* __restrict__ bq, const float* __restrict__ bk,
              const float* __restrict__ bv,
              __bf16* __restrict__ Qh, __bf16* __restrict__ Kh, __bf16* __restrict__ Vt) {
  __shared__ __bf16 As[128 * 32];
  __shared__ __bf16 Bs[128 * 32];
  const int which = blockIdx.x >> 8;          // 3 GEMMs of 256 tiles each
  int local = blockIdx.x & 255;
  local = (local & 7) * 32 + (local >> 3);    // XCD-contiguous swizzle (XCD = origIdx&7)
  const int m0 = (local >> 3) * 128, n0 = (local & 7) * 128;
  const __bf16* A    = which == 0 ? Aq  : which == 1 ? Ak  : Av;
  const __bf16* Bw   = which == 0 ? Wqb : which == 1 ? Wkb : Wvb;
  const float*  bias = which == 0 ? bq  : which == 1 ? bk  : bv;
  const int t = threadIdx.x;

  f32x4 acc[4][4] = {};
  gemm_core(A, Bw, As, Bs, m0, n0, t, acc);

  const int lane = t & 63, wv = t >> 6, lo = lane & 15, hi = lane >> 4;
  const int wm = (wv >> 1) * 64, wn = (wv & 1) * 64;

  if (which < 2) {
    __bf16* C = which ? Kh : Qh;              // head-major [B][H][S][64]
#pragma unroll
    for (int mi = 0; mi < 4; ++mi) {
      const int mbase = m0 + wm + mi * 16 + hi * 4;
      const int b = mbase >> 11, s = mbase & 2047;
#pragma unroll
      for (int ni = 0; ni < 4; ++ni) {
        const int n = n0 + wn + ni * 16 + lo;
        const int h = n >> 6, d = n & 63;
        const float bb = bias[n];
        __bf16* p = C + ((size_t)(b * Hc + h) * Sc + s) * 64 + d;
#pragma unroll
        for (int r = 0; r < 4; ++r)
          p[(size_t)r * 64] = (__bf16)(acc[mi][ni][r] + bb);
      }
    }
  } else {                                    // V transposed [B][H][64][S]
#pragma unroll
    for (int mi = 0; mi < 4; ++mi) {
      const int mbase = m0 + wm + mi * 16 + hi * 4;
      const int b = mbase >> 11, s0 = mbase & 2047;
#pragma unroll
      for (int ni = 0; ni < 4; ++ni) {
        const int n = n0 + wn + ni * 16 + lo;
        const int h = n >> 6, d = n & 63;
        const float bb = bias[n];
        bf16x4 pk;
#pragma unroll
        for (int r = 0; r < 4; ++r) pk[r] = (__bf16)(acc[mi][ni][r] + bb);
        *(bf16x4*)(Vt + ((size_t)(b * Hc + h) * 64 + d) * Sc + s0) = pk;
      }
    }
  }
}

// ---------------------------------------------------------------- output projection (fp32 out)
__global__ __launch_bounds__(256)
void gemm_o(const __bf16* __restrict__ A, const __bf16* __restrict__ Bw,
            const float* __restrict__ bias, float* __restrict__ C) {
  __shared__ __bf16 As[128 * 32];
  __shared__ __bf16 Bs[128 * 32];
  int bid = blockIdx.x;
  bid = (bid & 7) * 32 + (bid >> 3);
  const int m0 = (bid >> 3) * 128, n0 = (bid & 7) * 128;
  const int t = threadIdx.x;

  f32x4 acc[4][4] = {};
  gemm_core(A, Bw, As, Bs, m0, n0, t, acc);

  const int lane = t & 63, wv = t >> 6, lo = lane & 15, hi = lane >> 4;
  const int wm = (wv >> 1) * 64, wn = (wv & 1) * 64;
#pragma unroll
  for (int mi = 0; mi < 4; ++mi) {
    const int mbase = m0 + wm + mi * 16 + hi * 4;
#pragma unroll
    for (int ni = 0; ni < 4; ++ni) {
      const int n = n0 + wn + ni * 16 + lo;
      const float bb = bias[n];
#pragma unroll
      for (int r = 0; r < 4; ++r)
        C[(size_t)(mbase + r) * 1024 + n] = acc[mi][ni][r] + bb;
    }
  }
}

// ---------------------------------------------------------------- flash attention, swapped QK^T
// Qh,Kh: [B][H][S][64] ; Vt: [B][H][64][S] ; X out: [B*S][1024] bf16
// Block: 4 waves x 32 q-rows = 128 q. Each lane owns one q-row per 16-q subtile (lo).
// S^T = mfma(Kfrag, Qfrag): lane holds S^T[k=hi*4+r (per kc)][q=lo] -> softmax needs only
// in-lane reduce + shfl_xor(16,32). P stored [q][k] in LDS -> PV B-fragment is contiguous.
__global__ __launch_bounds__(256)
void attn_fwd(const __bf16* __restrict__ Qh, const __bf16* __restrict__ Kh,
              const __bf16* __restrict__ Vt, const unsigned long long* __restrict__ mbits,
              __bf16* __restrict__ X) {
  __shared__ __bf16 Ks[2][64 * 64];           // 8KB x2, XOR-swizzled rows
  __shared__ __bf16 Vs[2][64 * 64];           // 8KB x2, XOR-swizzled rows
  __shared__ __bf16 Pq[4][2][16][80];         // [wave][qt][q][k+pad] 20KB

  int bid = blockIdx.x;
  bid = (bid & 7) * 64 + (bid >> 3);          // XCD swizzle (512 = 8*64)
  const int qblk = bid & 15, h = (bid >> 4) & 15, b = bid >> 8;
  const int t = threadIdx.x, lane = t & 63, wv = t >> 6;
  const int lo = lane & 15, hi = lane >> 4;
  const int q0 = qblk * 128 + wv * 32;

  const size_t headoff = (size_t)(b * Hc + h) * Sc * 64;
  const __bf16* Qp = Qh + headoff + (size_t)q0 * 64;
  const __bf16* Kp = Kh + headoff;            // [S][64]
  const __bf16* Vp = Vt + headoff;            // [64][S]

  bf16x8 qf[2][2];
#pragma unroll
  for (int qt = 0; qt < 2; ++qt)
#pragma unroll
    for (int c = 0; c < 2; ++c)
      qf[qt][c] = *(const bf16x8*)&Qp[(qt * 16 + lo) * 64 + c * 32 + hi * 8];

  f32x4 o[2][4] = {};
  float mr[2] = {-1e30f, -1e30f}, lr[2] = {0.f, 0.f};

  // staging: thread t fills LDS row = t>>3, col-block = t&7 (linear dest);
  // source col pre-swizzled so swizzled READS are bank-spread (m201 pattern)
  const int srow = t >> 3, scb = t & 7;
  const int ksrc = ((scb ^ (srow & 7)) * 8);

  auto stage = [&](int buf, int kb) {
    async16(&Ks[buf][t * 8],        Kp + (size_t)(kb + srow) * 64 + ksrc);
    async16(&Ks[buf][t * 8 + 2048], Kp + (size_t)(kb + srow + 32) * 64 + ksrc);
    async16(&Vs[buf][t * 8],        Vp + (size_t)srow * Sc + kb + ksrc);
    async16(&Vs[buf][t * 8 + 2048], Vp + (size_t)(srow + 32) * Sc + kb + ksrc);
  };

  stage(0, 0);
  int cur = 0;
  const int xr = (lo & 7) << 3;               // elem-space XOR for swizzled reads

  for (int kb = 0; kb < Sc; kb += 64) {
    __syncthreads();                          // drains prev staging (vmcnt) + prev reads
    if (kb + 64 < Sc) stage(cur ^ 1, kb + 64);

    bf16x8 kf[4][2];                          // K fragments, shared across both q-tiles
#pragma unroll
    for (int kc = 0; kc < 4; ++kc)
#pragma unroll
      for (int c = 0; c < 2; ++c)
        kf[kc][c] = *(const bf16x8*)&Ks[cur][(kc * 16 + lo) * 64 + ((c * 32 + hi * 8) ^ xr)];

#pragma unroll
    for (int qt = 0; qt < 2; ++qt) {
      f32x4 sc[4];
#pragma unroll
      for (int kc = 0; kc < 4; ++kc) {
        f32x4 z = {0.f, 0.f, 0.f, 0.f};
        sc[kc] = __builtin_amdgcn_mfma_f32_16x16x32_bf16(kf[kc][0], qf[qt][0], z, 0, 0, 0);
        sc[kc] = __builtin_amdgcn_mfma_f32_16x16x32_bf16(kf[kc][1], qf[qt][1], sc[kc], 0, 0, 0);
      }
      const unsigned long long mb =
          mbits[(size_t)(b * Sc + q0 + qt * 16 + lo) * (Sc / 64) + (kb >> 6)];
      const bool allm = __all(mb == ~0ull);
      float pvv[4][4];
#pragma unroll
      for (int kc = 0; kc < 4; ++kc)
#pragma unroll
        for (int r = 0; r < 4; ++r) pvv[kc][r] = sc[kc][r] * 0.125f;
      if (!allm) {
#pragma unroll
        for (int kc = 0; kc < 4; ++kc)
#pragma unroll
          for (int r = 0; r < 4; ++r)
            if (!((mb >> (kc * 16 + hi * 4 + r)) & 1ull)) pvv[kc][r] = -1e-9f;
      }
      float pmax = -1e30f;
#pragma unroll
      for (int kc = 0; kc < 4; ++kc)
#pragma unroll
        for (int r = 0; r < 4; ++r) pmax = fmaxf(pmax, pvv[kc][r]);
      pmax = fmaxf(pmax, __shfl_xor(pmax, 16));
      pmax = fmaxf(pmax, __shfl_xor(pmax, 32));

      float m = mr[qt];
      if (!__all(pmax <= m + 8.f)) {          // T13 defer-max
        const float mn = fmaxf(m, pmax);
        const float fs = exp2f((m - mn) * LOG2E);
        lr[qt] *= fs;
#pragma unroll
        for (int d0 = 0; d0 < 4; ++d0) o[qt][d0] *= fs;
        m = mn; mr[qt] = mn;
      }
      const float mj = m * LOG2E;
      float rs = 0.f;
#pragma unroll
      for (int kc = 0; kc < 4; ++kc)
#pragma unroll
        for (int r = 0; r < 4; ++r) {
          const float p = exp2f(__builtin_fmaf(pvv[kc][r], LOG2E, -mj));
          pvv[kc][r] = p; rs += p;
        }
      rs += __shfl_xor(rs, 16);
      rs += __shfl_xor(rs, 32);
      lr[qt] += rs;
#pragma unroll
      for (int kc = 0; kc < 4; ++kc) {        // P[q][k] -> LDS, 4x ds_write_b64
        bf16x4 pk;
#pragma unroll
        for (int r = 0; r < 4; ++r) pk[r] = (__bf16)pvv[kc][r];
        *(bf16x4*)&Pq[wv][qt][lo][kc * 16 + hi * 4] = pk;
      }
    }

    bf16x8 vf[4][2];                          // V^T fragments, shared across q-tiles
#pragma unroll
    for (int d0 = 0; d0 < 4; ++d0)
#pragma unroll
      for (int c = 0; c < 2; ++c)
        vf[d0][c] = *(const bf16x8*)&Vs[cur][(d0 * 16 + lo) * 64 + ((c * 32 + hi * 8) ^ xr)];
#pragma unroll
    for (int qt = 0; qt < 2; ++qt) {
      bf16x8 pa[2];
#pragma unroll
      for (int c = 0; c < 2; ++c)
        pa[c] = *(const bf16x8*)&Pq[wv][qt][lo][c * 32 + hi * 8];
#pragma unroll
      for (int d0 = 0; d0 < 4; ++d0) {
        o[qt][d0] = __builtin_amdgcn_mfma_f32_16x16x32_bf16(vf[d0][0], pa[0], o[qt][d0], 0, 0, 0);
        o[qt][d0] = __builtin_amdgcn_mfma_f32_16x16x32_bf16(vf[d0][1], pa[1], o[qt][d0], 0, 0, 0);
      }
    }
    cur ^= 1;
  }

#pragma unroll
  for (int qt = 0; qt < 2; ++qt) {
    const float inv = 1.f / lr[qt];
#pragma unroll
    for (int d0 = 0; d0 < 4; ++d0) {
      bf16x4 st;
#pragma unroll
      for (int r = 0; r < 4; ++r) st[r] = (__bf16)(o[qt][d0][r] * inv);
      *(bf16x4*)&X[(size_t)(b * Sc + q0 + qt * 16 + lo) * 1024 + h * 64 + d0 * 16 + hi * 4] = st;
    }
  }
}

// ---------------------------------------------------------------- launcher
extern "C" void kernel_launch(void* const* d_in, const int* in_sizes, int n_in,
                              void* d_out, int out_size, void* d_ws, size_t ws_size,
                              hipStream_t stream) {
  const float* q  = (const float*)d_in[0];
  const float* k  = (const float*)d_in[1];
  const float* v  = (const float*)d_in[2];
  const int*   mask = (const int*)d_in[3];
  const float* Wq = (const float*)d_in[4];
  const float* bq = (const float*)d_in[5];
  const float* Wk = (const float*)d_in[6];
  const float* bk = (const float*)d_in[7];
  const float* Wv = (const float*)d_in[8];
  const float* bv = (const float*)d_in[9];
  const float* Wo = (const float*)d_in[10];
  const float* bo = (const float*)d_in[11];

  const size_t MB = 1u << 20;
  if (ws_size < 66 * MB) return;

  char* ws = (char*)d_ws;
  __bf16* wqb  = (__bf16*)(ws + 0 * MB);
  __bf16* wkb  = (__bf16*)(ws + 2 * MB);
  __bf16* wvb  = (__bf16*)(ws + 4 * MB);
  __bf16* wob  = (__bf16*)(ws + 6 * MB);
  __bf16* qbin = (__bf16*)(ws + 8 * MB);
  __bf16* kbin = (__bf16*)(ws + 16 * MB);
  __bf16* vbin = (__bf16*)(ws + 24 * MB);
  __bf16* Qh   = (__bf16*)(ws + 32 * MB);
  __bf16* Kh   = (__bf16*)(ws + 40 * MB);
  __bf16* Vt   = (__bf16*)(ws + 48 * MB);
  __bf16* Xat  = (__bf16*)(ws + 56 * MB);
  unsigned long long* mbits = (unsigned long long*)(ws + 64 * MB);

  const int nIn8 = Mrows * Dm / 8;   // 524288
  const int nW8  = Dm * Dm / 8;      // 131072
  cvt3<<<nIn8 / 256, 256, 0, stream>>>(q, k, v, qbin, kbin, vbin, nIn8);
  cvt4<<<nW8 / 256, 256, 0, stream>>>(Wq, Wk, Wv, Wo, wqb, wkb, wvb, wob, nW8);
  pack_mask<<<4096, 256, 0, stream>>>(mask, mbits);

  gemm_qkv<<<768, 256, 0, stream>>>(qbin, kbin, vbin, wqb, wkb, wvb, bq, bk, bv, Qh, Kh, Vt);

  attn_fwd<<<512, 256, 0, stream>>>(Qh, Kh, Vt, mbits, Xat);

  gemm_o<<<256, 256, 0, stream>>>(Xat, wob, bo, (float*)d_out);
}

// Round 4
// 284.451 us; speedup vs baseline: 1.7679x; 1.0916x over previous
//
#include <hip/hip_runtime.h>
#include <hip/hip_bf16.h>
#include <stdint.h>

#define DI __device__ __forceinline__

typedef __bf16 bf16x8 __attribute__((ext_vector_type(8)));
typedef __bf16 bf16x4 __attribute__((ext_vector_type(4)));
typedef float  f32x4  __attribute__((ext_vector_type(4)));

constexpr int Bc = 2, Sc = 2048, Dm = 1024, Hc = 16;
constexpr int Mrows = Bc * Sc;          // 4096
constexpr float LOG2E = 1.4426950408889634f;

// ---------------------------------------------------------------- async 16B global->LDS
DI void async16(void* lds, const void* g) {
  __builtin_amdgcn_global_load_lds(
      (const __attribute__((address_space(1))) void*)g,
      (__attribute__((address_space(3))) void*)lds, 16, 0, 0);
}

// ---------------------------------------------------------------- fp32 -> bf16 fused converters
DI void cvt_one(const float* __restrict__ in, __bf16* __restrict__ out, int i) {
  const f32x4* in4 = (const f32x4*)in;
  f32x4 a = in4[2 * i], b = in4[2 * i + 1];
  bf16x8 o;
#pragma unroll
  for (int j = 0; j < 4; ++j) { o[j] = (__bf16)a[j]; o[4 + j] = (__bf16)b[j]; }
  ((bf16x8*)out)[i] = o;
}

__global__ void cvt3(const float* __restrict__ a, const float* __restrict__ b,
                     const float* __restrict__ c, __bf16* __restrict__ oa,
                     __bf16* __restrict__ ob, __bf16* __restrict__ oc, int n8) {
  int i = blockIdx.x * blockDim.x + threadIdx.x;
  if (i >= n8) return;
  cvt_one(a, oa, i); cvt_one(b, ob, i); cvt_one(c, oc, i);
}

__global__ void cvt4(const float* __restrict__ a, const float* __restrict__ b,
                     const float* __restrict__ c, const float* __restrict__ d,
                     __bf16* __restrict__ oa, __bf16* __restrict__ ob,
                     __bf16* __restrict__ oc, __bf16* __restrict__ od, int n8) {
  int i = blockIdx.x * blockDim.x + threadIdx.x;
  if (i >= n8) return;
  cvt_one(a, oa, i); cvt_one(b, ob, i); cvt_one(c, oc, i); cvt_one(d, od, i);
}

// ---------------------------------------------------------------- mask int32 -> bitmask
__global__ void pack_mask(const int* __restrict__ m, unsigned long long* __restrict__ bits) {
  const int total = Bc * Sc * Sc;
  const int nth = gridDim.x * blockDim.x;
  for (int i = blockIdx.x * blockDim.x + threadIdx.x; i < total; i += nth) {
    unsigned long long b = __ballot(m[i] != 0);
    if ((threadIdx.x & 63) == 0) bits[i >> 6] = b;
  }
}

// ---------------------------------------------------------------- GEMM core: 128x128 tile, K=1024
// 2-phase double-buffer: stage tile k+1 BEFORE computing tile k; one barrier per K-step.
// As/Bs are [2][4096] element double buffers.
DI void gemm_core(const __bf16* __restrict__ A, const __bf16* __restrict__ Bw,
                  __bf16* As, __bf16* Bs, int m0, int n0, int t, f32x4 (&acc)[4][4]) {
  const int lane = t & 63, wv = t >> 6;
  const int lo = lane & 15, hi = lane >> 4;
  const int wm = (wv >> 1) * 64, wn = (wv & 1) * 64;
  const int rowA = t >> 2, kc8 = (t & 3) * 8;

  auto stage = [&](int buf, int k0) {
    __bf16* as = As + buf * 4096;
    __bf16* bs = Bs + buf * 4096;
    async16(&as[t * 8],        A  + (size_t)(m0 + rowA) * 1024      + k0 + kc8);
    async16(&as[t * 8 + 2048], A  + (size_t)(m0 + rowA + 64) * 1024 + k0 + kc8);
    async16(&bs[t * 8],        Bw + (size_t)(n0 + rowA) * 1024      + k0 + kc8);
    async16(&bs[t * 8 + 2048], Bw + (size_t)(n0 + rowA + 64) * 1024 + k0 + kc8);
  };

  stage(0, 0);
  __syncthreads();                          // drain prologue loads (vmcnt 0 + barrier)
  int cur = 0;
  for (int k0 = 0; k0 < 1024; k0 += 32) {
    if (k0 + 32 < 1024) stage(cur ^ 1, k0 + 32);   // prefetch next tile (hidden under compute)
    const __bf16* as = As + cur * 4096;
    const __bf16* bs = Bs + cur * 4096;
    bf16x8 af[4], bfr[4];
#pragma unroll
    for (int i = 0; i < 4; ++i)
      af[i] = *(const bf16x8*)&as[(wm + i * 16 + lo) * 32 + hi * 8];
#pragma unroll
    for (int j = 0; j < 4; ++j)
      bfr[j] = *(const bf16x8*)&bs[(wn + j * 16 + lo) * 32 + hi * 8];
#pragma unroll
    for (int i = 0; i < 4; ++i)
#pragma unroll
      for (int j = 0; j < 4; ++j)
        acc[i][j] = __builtin_amdgcn_mfma_f32_16x16x32_bf16(af[i], bfr[j], acc[i][j], 0, 0, 0);
    __syncthreads();                        // drains prefetch; protects buf cur for re-stage
    cur ^= 1;
  }
}

// ---------------------------------------------------------------- fused QKV projection
// which=0: Q -> Qh [B][H][S][64] ; which=1: K -> Kh same ; which=2: V -> Vt [B][H][64][S]
__global__ __launch_bounds__(256, 3)
void gemm_qkv(const __bf16* __restrict__ Aq, const __bf16* __restrict__ Ak,
              const __bf16* __restrict__ Av, const __bf16* __restrict__ Wqb,
              const __bf16* __restrict__ Wkb, const __bf16* __restrict__ Wvb,
              const float* __restrict__ bq, const float* __restrict__ bk,
              const float* __restrict__ bv,
              __bf16* __restrict__ Qh, __bf16* __restrict__ Kh, __bf16* __restrict__ Vt) {
  __shared__ __bf16 As[2][128 * 32];
  __shared__ __bf16 Bs[2][128 * 32];
  const int which = blockIdx.x >> 8;          // 3 GEMMs of 256 tiles each
  int local = blockIdx.x & 255;
  local = (local & 7) * 32 + (local >> 3);    // XCD-contiguous swizzle (XCD = origIdx&7)
  const int m0 = (local >> 3) * 128, n0 = (local & 7) * 128;
  const __bf16* A    = which == 0 ? Aq  : which == 1 ? Ak  : Av;
  const __bf16* Bw   = which == 0 ? Wqb : which == 1 ? Wkb : Wvb;
  const float*  bias = which == 0 ? bq  : which == 1 ? bk  : bv;
  const int t = threadIdx.x;

  f32x4 acc[4][4] = {};
  gemm_core(A, Bw, &As[0][0], &Bs[0][0], m0, n0, t, acc);

  const int lane = t & 63, wv = t >> 6, lo = lane & 15, hi = lane >> 4;
  const int wm = (wv >> 1) * 64, wn = (wv & 1) * 64;

  if (which < 2) {
    __bf16* C = which ? Kh : Qh;              // head-major [B][H][S][64]
#pragma unroll
    for (int mi = 0; mi < 4; ++mi) {
      const int mbase = m0 + wm + mi * 16 + hi * 4;
      const int b = mbase >> 11, s = mbase & 2047;
#pragma unroll
      for (int ni = 0; ni < 4; ++ni) {
        const int n = n0 + wn + ni * 16 + lo;
        const int h = n >> 6, d = n & 63;
        const float bb = bias[n];
        __bf16* p = C + ((size_t)(b * Hc + h) * Sc + s) * 64 + d;
#pragma unroll
        for (int r = 0; r < 4; ++r)
          p[(size_t)r * 64] = (__bf16)(acc[mi][ni][r] + bb);
      }
    }
  } else {                                    // V transposed [B][H][64][S]
#pragma unroll
    for (int mi = 0; mi < 4; ++mi) {
      const int mbase = m0 + wm + mi * 16 + hi * 4;
      const int b = mbase >> 11, s0 = mbase & 2047;
#pragma unroll
      for (int ni = 0; ni < 4; ++ni) {
        const int n = n0 + wn + ni * 16 + lo;
        const int h = n >> 6, d = n & 63;
        const float bb = bias[n];
        bf16x4 pk;
#pragma unroll
        for (int r = 0; r < 4; ++r) pk[r] = (__bf16)(acc[mi][ni][r] + bb);
        *(bf16x4*)(Vt + ((size_t)(b * Hc + h) * 64 + d) * Sc + s0) = pk;
      }
    }
  }
}

// ---------------------------------------------------------------- output projection (fp32 out)
__global__ __launch_bounds__(256, 3)
void gemm_o(const __bf16* __restrict__ A, const __bf16* __restrict__ Bw,
            const float* __restrict__ bias, float* __restrict__ C) {
  __shared__ __bf16 As[2][128 * 32];
  __shared__ __bf16 Bs[2][128 * 32];
  int bid = blockIdx.x;
  bid = (bid & 7) * 32 + (bid >> 3);
  const int m0 = (bid >> 3) * 128, n0 = (bid & 7) * 128;
  const int t = threadIdx.x;

  f32x4 acc[4][4] = {};
  gemm_core(A, Bw, &As[0][0], &Bs[0][0], m0, n0, t, acc);

  const int lane = t & 63, wv = t >> 6, lo = lane & 15, hi = lane >> 4;
  const int wm = (wv >> 1) * 64, wn = (wv & 1) * 64;
#pragma unroll
  for (int mi = 0; mi < 4; ++mi) {
    const int mbase = m0 + wm + mi * 16 + hi * 4;
#pragma unroll
    for (int ni = 0; ni < 4; ++ni) {
      const int n = n0 + wn + ni * 16 + lo;
      const float bb = bias[n];
#pragma unroll
      for (int r = 0; r < 4; ++r)
        C[(size_t)(mbase + r) * 1024 + n] = acc[mi][ni][r] + bb;
    }
  }
}

// ---------------------------------------------------------------- flash attention, swapped QK^T
// Qh,Kh: [B][H][S][64] ; Vt: [B][H][64][S] ; X out: [B*S][1024] bf16
// Block: 8 waves x 16 q-rows = 128 q (512 threads). Each lane owns one q-row (lo).
// S^T = mfma(Kfrag, Qfrag): lane holds S^T[k=kc*16+hi*4+r][q=lo] -> softmax is in-lane
// reduce + shfl_xor(16,32). P stored [q][k] (stride 72: conflict-free) -> PV B-fragment.
__global__ __launch_bounds__(512, 4)
void attn_fwd(const __bf16* __restrict__ Qh, const __bf16* __restrict__ Kh,
              const __bf16* __restrict__ Vt, const unsigned long long* __restrict__ mbits,
              __bf16* __restrict__ X) {
  __shared__ __bf16 Ks[2][64 * 64];           // 8KB x2, XOR-swizzled cols
  __shared__ __bf16 Vs[2][64 * 64];           // 8KB x2, XOR-swizzled cols
  __shared__ __bf16 Pq[8][16][72];            // [wave][q][k+pad] 18KB, stride 36 dwords (≡4 mod 32)

  int bid = blockIdx.x;
  bid = (bid & 7) * 64 + (bid >> 3);          // XCD swizzle (512 = 8*64)
  const int qblk = bid & 15, h = (bid >> 4) & 15, b = bid >> 8;
  const int t = threadIdx.x, lane = t & 63, wv = t >> 6;
  const int lo = lane & 15, hi = lane >> 4;
  const int q0 = qblk * 128 + wv * 16;

  const size_t headoff = (size_t)(b * Hc + h) * Sc * 64;
  const __bf16* Qp = Qh + headoff + (size_t)q0 * 64;
  const __bf16* Kp = Kh + headoff;            // [S][64]
  const __bf16* Vp = Vt + headoff;            // [64][S]

  bf16x8 qf[2];
#pragma unroll
  for (int c = 0; c < 2; ++c)
    qf[c] = *(const bf16x8*)&Qp[lo * 64 + c * 32 + hi * 8];

  f32x4 o[4] = {};
  float mr = -1e30f, lr = 0.f;

  // staging: 512 threads, thread t fills LDS row = t>>3 (0..63), col-block = t&7 (linear dest);
  // source col pre-swizzled so swizzled READS are bank-spread (m201 pattern)
  const int srow = t >> 3, scb = t & 7;
  const int ksrc = ((scb ^ (srow & 7)) * 8);

  auto stage = [&](int buf, int kb) {
    async16(&Ks[buf][t * 8], Kp + (size_t)(kb + srow) * 64 + ksrc);
    async16(&Vs[buf][t * 8], Vp + (size_t)srow * Sc + kb + ksrc);
  };

  stage(0, 0);
  int cur = 0;
  const int xr = (lo & 7) << 3;               // elem-space XOR for swizzled reads
  const unsigned long long* mrow = mbits + (size_t)(b * Sc + q0 + lo) * (Sc / 64);

  for (int kb = 0; kb < Sc; kb += 64) {
    __syncthreads();                          // drains prev staging (vmcnt) + prev reads
    if (kb + 64 < Sc) stage(cur ^ 1, kb + 64);

    // ---- S^T tile: 64 keys x 16 q
    f32x4 sc[4];
    __builtin_amdgcn_s_setprio(1);
#pragma unroll
    for (int kc = 0; kc < 4; ++kc) {
      bf16x8 kf0 = *(const bf16x8*)&Ks[cur][(kc * 16 + lo) * 64 + ((hi * 8) ^ xr)];
      bf16x8 kf1 = *(const bf16x8*)&Ks[cur][(kc * 16 + lo) * 64 + ((32 + hi * 8) ^ xr)];
      f32x4 z = {0.f, 0.f, 0.f, 0.f};
      sc[kc] = __builtin_amdgcn_mfma_f32_16x16x32_bf16(kf0, qf[0], z, 0, 0, 0);
      sc[kc] = __builtin_amdgcn_mfma_f32_16x16x32_bf16(kf1, qf[1], sc[kc], 0, 0, 0);
    }
    __builtin_amdgcn_s_setprio(0);

    const unsigned long long mb = mrow[kb >> 6];
    const bool allm = __all(mb == ~0ull);
    float pvv[4][4];
#pragma unroll
    for (int kc = 0; kc < 4; ++kc)
#pragma unroll
      for (int r = 0; r < 4; ++r) pvv[kc][r] = sc[kc][r] * 0.125f;
    if (!allm) {
#pragma unroll
      for (int kc = 0; kc < 4; ++kc)
#pragma unroll
        for (int r = 0; r < 4; ++r)
          if (!((mb >> (kc * 16 + hi * 4 + r)) & 1ull)) pvv[kc][r] = -1e-9f;
    }
    float pmax = -1e30f;
#pragma unroll
    for (int kc = 0; kc < 4; ++kc)
#pragma unroll
      for (int r = 0; r < 4; ++r) pmax = fmaxf(pmax, pvv[kc][r]);
    pmax = fmaxf(pmax, __shfl_xor(pmax, 16));
    pmax = fmaxf(pmax, __shfl_xor(pmax, 32));

    if (!__all(pmax <= mr + 8.f)) {           // T13 defer-max
      const float mn = fmaxf(mr, pmax);
      const float fs = exp2f((mr - mn) * LOG2E);
      lr *= fs;
#pragma unroll
      for (int d0 = 0; d0 < 4; ++d0) o[d0] *= fs;
      mr = mn;
    }
    const float mj = mr * LOG2E;
    float rs = 0.f;
#pragma unroll
    for (int kc = 0; kc < 4; ++kc)
#pragma unroll
      for (int r = 0; r < 4; ++r) {
        const float p = exp2f(__builtin_fmaf(pvv[kc][r], LOG2E, -mj));
        pvv[kc][r] = p; rs += p;
      }
    rs += __shfl_xor(rs, 16);
    rs += __shfl_xor(rs, 32);
    lr += rs;

#pragma unroll
    for (int kc = 0; kc < 4; ++kc) {          // P[q][k] -> LDS, 4x ds_write_b64
      bf16x4 pk;
#pragma unroll
      for (int r = 0; r < 4; ++r) pk[r] = (__bf16)pvv[kc][r];
      *(bf16x4*)&Pq[wv][lo][kc * 16 + hi * 4] = pk;
    }

    // ---- O += P V  (A = V^T fragment from swizzled LDS, B = P fragment)
    bf16x8 pa[2];
#pragma unroll
    for (int c = 0; c < 2; ++c)
      pa[c] = *(const bf16x8*)&Pq[wv][lo][c * 32 + hi * 8];
    __builtin_amdgcn_s_setprio(1);
#pragma unroll
    for (int d0 = 0; d0 < 4; ++d0) {
      bf16x8 vf0 = *(const bf16x8*)&Vs[cur][(d0 * 16 + lo) * 64 + ((hi * 8) ^ xr)];
      bf16x8 vf1 = *(const bf16x8*)&Vs[cur][(d0 * 16 + lo) * 64 + ((32 + hi * 8) ^ xr)];
      o[d0] = __builtin_amdgcn_mfma_f32_16x16x32_bf16(vf0, pa[0], o[d0], 0, 0, 0);
      o[d0] = __builtin_amdgcn_mfma_f32_16x16x32_bf16(vf1, pa[1], o[d0], 0, 0, 0);
    }
    __builtin_amdgcn_s_setprio(0);
    cur ^= 1;
  }

  const float inv = 1.f / lr;
#pragma unroll
  for (int d0 = 0; d0 < 4; ++d0) {
    bf16x4 st;
#pragma unroll
    for (int r = 0; r < 4; ++r) st[r] = (__bf16)(o[d0][r] * inv);
    *(bf16x4*)&X[(size_t)(b * Sc + q0 + lo) * 1024 + h * 64 + d0 * 16 + hi * 4] = st;
  }
}

// ---------------------------------------------------------------- launcher
extern "C" void kernel_launch(void* const* d_in, const int* in_sizes, int n_in,
                              void* d_out, int out_size, void* d_ws, size_t ws_size,
                              hipStream_t stream) {
  const float* q  = (const float*)d_in[0];
  const float* k  = (const float*)d_in[1];
  const float* v  = (const float*)d_in[2];
  const int*   mask = (const int*)d_in[3];
  const float* Wq = (const float*)d_in[4];
  const float* bq = (const float*)d_in[5];
  const float* Wk = (const float*)d_in[6];
  const float* bk = (const float*)d_in[7];
  const float* Wv = (const float*)d_in[8];
  const float* bv = (const float*)d_in[9];
  const float* Wo = (const float*)d_in[10];
  const float* bo = (const float*)d_in[11];

  const size_t MB = 1u << 20;
  if (ws_size < 66 * MB) return;

  char* ws = (char*)d_ws;
  __bf16* wqb  = (__bf16*)(ws + 0 * MB);
  __bf16* wkb  = (__bf16*)(ws + 2 * MB);
  __bf16* wvb  = (__bf16*)(ws + 4 * MB);
  __bf16* wob  = (__bf16*)(ws + 6 * MB);
  __bf16* qbin = (__bf16*)(ws + 8 * MB);
  __bf16* kbin = (__bf16*)(ws + 16 * MB);
  __bf16* vbin = (__bf16*)(ws + 24 * MB);
  __bf16* Qh   = (__bf16*)(ws + 32 * MB);
  __bf16* Kh   = (__bf16*)(ws + 40 * MB);
  __bf16* Vt   = (__bf16*)(ws + 48 * MB);
  __bf16* Xat  = (__bf16*)(ws + 56 * MB);
  unsigned long long* mbits = (unsigned long long*)(ws + 64 * MB);

  const int nIn8 = Mrows * Dm / 8;   // 524288
  const int nW8  = Dm * Dm / 8;      // 131072
  cvt3<<<nIn8 / 256, 256, 0, stream>>>(q, k, v, qbin, kbin, vbin, nIn8);
  cvt4<<<nW8 / 256, 256, 0, stream>>>(Wq, Wk, Wv, Wo, wqb, wkb, wvb, wob, nW8);
  pack_mask<<<4096, 256, 0, stream>>>(mask, mbits);

  gemm_qkv<<<768, 256, 0, stream>>>(qbin, kbin, vbin, wqb, wkb, wvb, bq, bk, bv, Qh, Kh, Vt);

  attn_fwd<<<512, 512, 0, stream>>>(Qh, Kh, Vt, mbits, Xat);

  gemm_o<<<256, 256, 0, stream>>>(Xat, wob, bo, (float*)d_out);
}